// Round 1
// baseline (4223.645 us; speedup 1.0000x reference)
//
#include <hip/hip_runtime.h>

typedef unsigned short u16;
typedef unsigned int u32;
typedef unsigned long long u64;
typedef int   v4i __attribute__((ext_vector_type(4)));
typedef short v8s __attribute__((ext_vector_type(8)));
typedef float v4f __attribute__((ext_vector_type(4)));

#define B_ 256
#define T_ 120
#define E_ 256
#define H_ 1024
#define K_ 1280     // E_ + H_
#define LDA 1288    // K_ + 8 pad (2-way LDS aliasing = free)

// ---- ws layout (bytes) ----
#define WS_WF   0                    // 10,485,760  (W fragments, bf16)
#define WS_X    10485760             // 15,728,640  (X (T,B,E) bf16)
#define WS_HS   26214400             // 62,914,560  (hs (T,B,H) bf16)
#define WS_BAR  89128960             // 3,840       (8 groups x 120 steps u32)

__device__ __forceinline__ u16 f2bf(float f) {
    union { float f; u32 u; } v; v.f = f;
    u32 r = v.u + 0x7fffu + ((v.u >> 16) & 1u);   // RNE
    return (u16)(r >> 16);
}
__device__ __forceinline__ float bf2f(u16 u) {
    union { u32 u; float f; } v; v.u = ((u32)u) << 16; return v.f;
}
__device__ __forceinline__ float fsig(float x) {
    float t = __builtin_amdgcn_exp2f(-1.44269504f * x);
    return __builtin_amdgcn_rcpf(1.0f + t);
}
__device__ __forceinline__ float ftanh_(float x) {
    float xc = fminf(8.0f, fmaxf(-8.0f, x));
    float t = __builtin_amdgcn_exp2f(2.88539008f * xc);
    return (t - 1.0f) * __builtin_amdgcn_rcpf(t + 1.0f);
}

// ---------------- P1: W (1280,4096) f32 -> bf16 B-operand fragments ----------------
// Fragment order: for (nc 0..31, g 0..3): wave chunk of 40960 bf16 =
//   [s 0..39][tno 0..1][lane 0..63][j 0..7], elem = W[32s + (lane>>4)*8 + j][g*1024 + nc*32 + tno*16 + (lane&15)]
__global__ void prep_w(const float* __restrict__ W, u16* __restrict__ Wf) {
    int tg  = blockIdx.x * 256 + threadIdx.x;     // < 655360
    int l   = tg & 63;
    int fid = tg >> 6;                            // < 10240
    int tno = fid & 1;
    int s   = (fid >> 1) % 40;
    int gg  = (fid >> 1) / 40;                    // nc*4 + g
    int g   = gg & 3, nc = gg >> 2;
    int kb  = s * 32 + ((l >> 4) << 3);
    int c   = g * 1024 + nc * 32 + tno * 16 + (l & 15);
    u16 o[8];
#pragma unroll
    for (int j = 0; j < 8; ++j)
        o[j] = f2bf(W[(size_t)(kb + j) * 4096 + c]);
    *(v4i*)(Wf + (((size_t)fid << 6) + l) * 8) = *(v4i*)o;
}

// ---------------- P2: embedding gather -> X (T,B,E) bf16 ----------------
__global__ void prep_x(const int* __restrict__ tokens, const float* __restrict__ emb,
                       u16* __restrict__ X) {
    int v   = blockIdx.x * 256 + threadIdx.x;     // < 983040
    int e8  = v & 31;
    int row = v >> 5;                             // t*256 + b
    int t = row >> 8, b = row & 255;
    int tok = tokens[b * T_ + t];
    const float* src = emb + (size_t)tok * E_ + e8 * 8;
    u16 o[8];
#pragma unroll
    for (int j = 0; j < 8; ++j) o[j] = f2bf(src[j]);
    *(v4i*)(X + (size_t)row * E_ + e8 * 8) = *(v4i*)o;
}

// ---------------- main persistent LSTM kernel ----------------
// 256 blocks (1/CU): block = (mchunk = bid&7, nc = bid>>3).
// Covers batch rows [mchunk*32, +32), hidden units [nc*32, +32), all 4 gates.
// Wave g computes gate g's 32x32 tile; W fragments resident in VGPRs (320/wave).
__global__ __launch_bounds__(256, 1) void lstm_main(
    const u16* __restrict__ Wf, const u16* __restrict__ X,
    const float* __restrict__ b_lstm, u16* __restrict__ hs,
    u32* __restrict__ bar) {

    __shared__ u16  A_lds[32 * LDA];      // 82,432 B
    __shared__ float gates[4 * 32 * 33];  // 16,896 B
    __shared__ float bias[4 * 32];

    const int tid  = threadIdx.x;
    const int lane = tid & 63;
    const int wv   = tid >> 6;            // gate id
    const int bid  = blockIdx.x;
    const int mchunk = bid & 7;
    const int nc   = bid >> 3;
    const int m0   = mchunk << 5;

    if (tid < 128) {
        int g = tid >> 5, n = tid & 31;
        bias[tid] = b_lstm[g * 1024 + (nc << 5) + n];
    }

    // Load resident W fragments: 80 x 16B per lane, contiguous & coalesced.
    v8s Wr[40][2];
    const v4i* wsrc = (const v4i*)(Wf + (size_t)(nc * 4 + wv) * 40960);
#pragma unroll
    for (int s = 0; s < 40; ++s)
#pragma unroll
        for (int tno = 0; tno < 2; ++tno)
            Wr[s][tno] = __builtin_bit_cast(v8s, wsrc[(s * 2 + tno) * 64 + lane]);

    float cst[4] = {0.f, 0.f, 0.f, 0.f};       // c-state, fixed ownership across steps
    const int cm  = tid >> 3;                   // cell row 0..31
    const int cn4 = (tid & 7) << 2;             // cell col group

    const int arow = lane & 15;
    const int aq   = (lane >> 4) << 3;
    const u16* Abase = &A_lds[arow * LDA + aq];

    for (int t = 0; t < T_; ++t) {
        // ---- stage A = [x_t | h_{t-1}] rows m0..m0+31 into LDS ----
        {
            const v4i* xs = (const v4i*)(X + ((size_t)t * B_ + m0) * E_);
#pragma unroll
            for (int i = 0; i < 4; ++i) {
                int idx = tid + i * 256;            // 0..1023
                int r = idx >> 5, c8 = idx & 31;
                v4i v = xs[r * 32 + c8];
                *(v4i*)&A_lds[r * LDA + c8 * 8] = v;
            }
            if (t == 0) {
#pragma unroll
                for (int i = 0; i < 16; ++i) {
                    int idx = tid + i * 256;        // 0..4095
                    int r = idx >> 7, k8 = idx & 127;
                    v4i z = {0, 0, 0, 0};
                    *(v4i*)&A_lds[r * LDA + 256 + k8 * 8] = z;
                }
            } else {
                const v4i* hsrc = (const v4i*)(hs + ((size_t)(t - 1) * B_ + m0) * H_);
#pragma unroll
                for (int i = 0; i < 16; ++i) {
                    int idx = tid + i * 256;
                    int r = idx >> 7, k8 = idx & 127;
                    v4i v = hsrc[r * 128 + k8];
                    *(v4i*)&A_lds[r * LDA + 256 + k8 * 8] = v;
                }
            }
        }
        __syncthreads();

        // ---- GEMM: 32(m) x 32(n, gate wv) x 1280(K), W from registers ----
        v4f acc00 = {0,0,0,0}, acc01 = {0,0,0,0}, acc10 = {0,0,0,0}, acc11 = {0,0,0,0};
#pragma unroll
        for (int s = 0; s < 40; ++s) {
            v8s a0 = *(const v8s*)(Abase + s * 32);
            v8s a1 = *(const v8s*)(Abase + 16 * LDA + s * 32);
            acc00 = __builtin_amdgcn_mfma_f32_16x16x32_bf16(a0, Wr[s][0], acc00, 0, 0, 0);
            acc01 = __builtin_amdgcn_mfma_f32_16x16x32_bf16(a0, Wr[s][1], acc01, 0, 0, 0);
            acc10 = __builtin_amdgcn_mfma_f32_16x16x32_bf16(a1, Wr[s][0], acc10, 0, 0, 0);
            acc11 = __builtin_amdgcn_mfma_f32_16x16x32_bf16(a1, Wr[s][1], acc11, 0, 0, 0);
        }

        // ---- gate exchange: C/D layout col=lane&15, row=quad*4+reg ----
#pragma unroll
        for (int r = 0; r < 4; ++r) {
            int mm = ((lane >> 4) << 2) + r;
            int nn = lane & 15;
            gates[wv * 1056 + mm * 33 + nn]             = acc00[r];
            gates[wv * 1056 + mm * 33 + 16 + nn]        = acc01[r];
            gates[wv * 1056 + (16 + mm) * 33 + nn]      = acc10[r];
            gates[wv * 1056 + (16 + mm) * 33 + 16 + nn] = acc11[r];
        }
        __syncthreads();

        // ---- cell math (f32), h -> bf16 to hs ----
        u64 hpack = 0;
#pragma unroll
        for (int q = 0; q < 4; ++q) {
            int n = cn4 + q;
            float ip = gates[0 * 1056 + cm * 33 + n] + bias[n];
            float jp = gates[1 * 1056 + cm * 33 + n] + bias[32 + n];
            float fp = gates[2 * 1056 + cm * 33 + n] + bias[64 + n] + 1.0f;
            float op = gates[3 * 1056 + cm * 33 + n] + bias[96 + n];
            float cc = fsig(fp) * cst[q] + fsig(ip) * ftanh_(jp);
            cst[q] = cc;
            float hh = fsig(op) * ftanh_(cc);
            hpack |= ((u64)f2bf(hh)) << (16 * q);
        }
        *(u64*)(hs + ((size_t)t * B_ + m0 + cm) * H_ + (nc << 5) + cn4) = hpack;

        // ---- per-m-group barrier (32 blocks), release/acquire at agent scope ----
        if (t < T_ - 1) {
            __threadfence();
            __syncthreads();
            if (tid == 0) {
                u32* p = &bar[mchunk * T_ + t];
                __hip_atomic_fetch_add(p, 1u, __ATOMIC_RELEASE, __HIP_MEMORY_SCOPE_AGENT);
                while (__hip_atomic_load(p, __ATOMIC_RELAXED, __HIP_MEMORY_SCOPE_AGENT) < 32u)
                    __builtin_amdgcn_s_sleep(2);
                __builtin_amdgcn_fence(__ATOMIC_ACQUIRE, "agent");
            }
            __syncthreads();
        }
    }
}

// ---------------- P3: preds = hs @ U + b2 ----------------
__global__ void proj_kernel(const u16* __restrict__ hs, const float* __restrict__ U,
                            const float* __restrict__ b2, float* __restrict__ out) {
    __shared__ float Ul[H_ * 5];    // 20,480 B
    int tid = threadIdx.x;
    for (int i = tid; i < H_ * 5; i += 256) Ul[i] = U[i];
    __syncthreads();
    int wv = tid >> 6, lane = tid & 63;
    int row = blockIdx.x * 4 + wv;          // t*256 + b, < 30720
    int t = row >> 8, b = row & 255;
    const v4i* hp = (const v4i*)(hs + (size_t)row * H_);
    float p[5] = {0.f, 0.f, 0.f, 0.f, 0.f};
#pragma unroll
    for (int half = 0; half < 2; ++half) {
        v4i hv = hp[lane * 2 + half];
        u16 us[8];
        *(v4i*)us = hv;
#pragma unroll
        for (int j = 0; j < 8; ++j) {
            float hf = bf2f(us[j]);
            int k = lane * 16 + half * 8 + j;
#pragma unroll
            for (int c = 0; c < 5; ++c) p[c] += hf * Ul[k * 5 + c];
        }
    }
#pragma unroll
    for (int c = 0; c < 5; ++c)
        for (int off = 32; off > 0; off >>= 1)
            p[c] += __shfl_down(p[c], off, 64);
    if (lane == 0) {
#pragma unroll
        for (int c = 0; c < 5; ++c)
            out[((size_t)b * T_ + t) * 5 + c] = p[c] + b2[c];
    }
}

extern "C" void kernel_launch(void* const* d_in, const int* in_sizes, int n_in,
                              void* d_out, int out_size, void* d_ws, size_t ws_size,
                              hipStream_t stream) {
    const int*   tokens = (const int*)d_in[0];
    const float* emb    = (const float*)d_in[1];
    const float* W      = (const float*)d_in[2];
    const float* b_l    = (const float*)d_in[3];
    const float* U      = (const float*)d_in[4];
    const float* b2     = (const float*)d_in[5];
    float* out = (float*)d_out;

    char* ws = (char*)d_ws;
    u16* Wf  = (u16*)(ws + WS_WF);
    u16* X   = (u16*)(ws + WS_X);
    u16* hs  = (u16*)(ws + WS_HS);
    u32* bar = (u32*)(ws + WS_BAR);

    hipMemsetAsync(bar, 0, 8 * T_ * sizeof(u32), stream);
    prep_w<<<2560, 256, 0, stream>>>(W, Wf);
    prep_x<<<3840, 256, 0, stream>>>(tokens, emb, X);
    lstm_main<<<256, 256, 0, stream>>>(Wf, X, b_l, hs, bar);
    proj_kernel<<<7680, 256, 0, stream>>>(hs, U, b2, out);
}

// Round 2
// 1180.137 us; speedup vs baseline: 3.5789x; 3.5789x over previous
//
#include <hip/hip_runtime.h>

typedef unsigned short u16;
typedef unsigned int u32;
typedef unsigned long long u64;
typedef int   v4i __attribute__((ext_vector_type(4)));
typedef short v8s __attribute__((ext_vector_type(8)));
typedef float v4f __attribute__((ext_vector_type(4)));

#define B_ 256
#define T_ 120
#define E_ 256
#define H_ 1024
#define K_ 1280     // E_ + H_
#define LDA 1288    // K_ + 8 pad

// ---- ws layout (bytes) ----
#define WS_WF   0                    // 10,485,760  (W fragments, bf16)
#define WS_X    10485760             // 15,728,640  (X (T,B,E) bf16)
#define WS_HS   26214400             // 62,914,560  (hs (T,B,H) bf16)
#define WS_BAR  89128960             // 3,840

__device__ __forceinline__ u16 f2bf(float f) {
    union { float f; u32 u; } v; v.f = f;
    u32 r = v.u + 0x7fffu + ((v.u >> 16) & 1u);   // RNE
    return (u16)(r >> 16);
}
__device__ __forceinline__ float bf2f(u16 u) {
    union { u32 u; float f; } v; v.u = ((u32)u) << 16; return v.f;
}
__device__ __forceinline__ float fsig(float x) {
    float t = __builtin_amdgcn_exp2f(-1.44269504f * x);
    return __builtin_amdgcn_rcpf(1.0f + t);
}
__device__ __forceinline__ float ftanh_(float x) {
    float xc = fminf(8.0f, fmaxf(-8.0f, x));
    float t = __builtin_amdgcn_exp2f(2.88539008f * xc);
    return (t - 1.0f) * __builtin_amdgcn_rcpf(t + 1.0f);
}

// ---------------- P1: W (1280,4096) f32 -> bf16 B-operand fragments ----------------
// Chunk per cid = (nc2*4 + g), nc2 = global 16-col group (0..63), g = gate (0..3).
// Within chunk: [s 0..39][lane 0..63][j 0..7],
//   elem = W[32s + (lane>>4)*8 + j][g*1024 + nc2*16 + (lane&15)]
__global__ void prep_w(const float* __restrict__ W, u16* __restrict__ Wf) {
    int tg  = blockIdx.x * 256 + threadIdx.x;     // < 655360
    int l   = tg & 63;
    int fid = tg >> 6;                            // < 10240
    int s   = fid % 40;
    int cid = fid / 40;                           // nc2*4 + g
    int g   = cid & 3, nc2 = cid >> 2;
    int kb  = s * 32 + ((l >> 4) << 3);
    int c   = g * 1024 + nc2 * 16 + (l & 15);
    u16 o[8];
#pragma unroll
    for (int j = 0; j < 8; ++j)
        o[j] = f2bf(W[(size_t)(kb + j) * 4096 + c]);
    *(v4i*)(Wf + (((size_t)fid << 6) + l) * 8) = *(v4i*)o;
}

// ---------------- P2: embedding gather -> X (T,B,E) bf16 ----------------
__global__ void prep_x(const int* __restrict__ tokens, const float* __restrict__ emb,
                       u16* __restrict__ X) {
    int v   = blockIdx.x * 256 + threadIdx.x;     // < 983040
    int e8  = v & 31;
    int row = v >> 5;                             // t*256 + b
    int t = row >> 8, b = row & 255;
    int tok = tokens[b * T_ + t];
    const float* src = emb + (size_t)tok * E_ + e8 * 8;
    u16 o[8];
#pragma unroll
    for (int j = 0; j < 8; ++j) o[j] = f2bf(src[j]);
    *(v4i*)(X + (size_t)row * E_ + e8 * 8) = *(v4i*)o;
}

// ---------------- main persistent LSTM kernel ----------------
// 256 blocks x 512 threads (8 waves = gate x 16-col half). Block = (mchunk=bid&7,
// nc=bid>>3): batch rows [mchunk*32,+32), hidden cols [nc*32,+32) of each gate.
// W resident: 160 VGPR/wave; 2 waves/SIMD. hs exchanged via agent-scope atomics
// (sc0 sc1 bypass L1/L2 -> NO buffer_wbl2 / buffer_inv anywhere in the loop).
__global__ __launch_bounds__(512, 2) void lstm_main(
    const u16* __restrict__ Wf, const u16* __restrict__ X,
    const float* __restrict__ b_lstm, u16* __restrict__ hs,
    u32* __restrict__ bar) {

    __shared__ u16  A_lds[32 * LDA];      // 82,432 B
    __shared__ float gates[4 * 32 * 33];  // 16,896 B
    __shared__ float bias[4 * 32];

    const int tid  = threadIdx.x;
    const int lane = tid & 63;
    const int wv   = tid >> 6;            // 0..7
    const int g    = wv >> 1;             // gate
    const int half = wv & 1;              // 16-col half
    const int bid  = blockIdx.x;
    const int mchunk = bid & 7;
    const int nc   = bid >> 3;
    const int m0   = mchunk << 5;

    if (tid < 128) bias[tid] = b_lstm[(tid >> 5) * H_ + (nc << 5) + (tid & 31)];

    // Resident W fragments: 40 x v8s = 160 VGPR.
    v8s Wr[40];
    {
        const int cid = (nc * 2 + half) * 4 + g;
        const v4i* wsrc = (const v4i*)(Wf + (size_t)cid * 40 * 512);
#pragma unroll
        for (int s = 0; s < 40; ++s)
            Wr[s] = __builtin_bit_cast(v8s, wsrc[s * 64 + lane]);
    }

    const u64* hu64 = (const u64*)hs;
    u32* hs32 = (u32*)hs;

    // Pre-loop: stage X_0 + zero h region of A.
    {
        const v4i* xs = (const v4i*)(X + (size_t)m0 * E_);
#pragma unroll
        for (int i = 0; i < 2; ++i) {
            int idx = tid + i * 512;          // < 1024
            int r = idx >> 5, c8 = idx & 31;
            *(v4i*)&A_lds[r * LDA + c8 * 8] = xs[r * 32 + c8];
        }
#pragma unroll
        for (int i = 0; i < 16; ++i) {
            int idx = tid + i * 512;          // < 8192
            int r = idx >> 8, c = idx & 255;
            *(u64*)&A_lds[r * LDA + 256 + c * 4] = 0ull;
        }
    }

    float cst[2] = {0.f, 0.f};
    const int cm  = tid >> 4;               // cell row 0..31
    const int cn2 = (tid & 15) << 1;        // cell col pair
    const u16* Abase = &A_lds[(lane & 15) * LDA + ((lane >> 4) << 3)];

    for (int t = 0; t < T_; ++t) {
        __syncthreads();                    // A (X_t | h_{t-1}) ready

        // ---- GEMM: 32(m) x 16(n) x 1280(K), W from registers ----
        v4f acc0 = {0,0,0,0}, acc1 = {0,0,0,0};
#pragma unroll
        for (int s = 0; s < 40; ++s) {
            v8s a0 = *(const v8s*)(Abase + s * 32);
            v8s a1 = *(const v8s*)(Abase + 16 * LDA + s * 32);
            acc0 = __builtin_amdgcn_mfma_f32_16x16x32_bf16(a0, Wr[s], acc0, 0, 0, 0);
            acc1 = __builtin_amdgcn_mfma_f32_16x16x32_bf16(a1, Wr[s], acc1, 0, 0, 0);
        }

        // ---- gate exchange: C/D layout col=lane&15, row=quad*4+reg ----
#pragma unroll
        for (int r = 0; r < 4; ++r) {
            int mm = ((lane >> 4) << 2) + r;
            int nn = (half << 4) + (lane & 15);
            gates[g * 1056 + mm * 33 + nn]        = acc0[r];
            gates[g * 1056 + (16 + mm) * 33 + nn] = acc1[r];
        }
        __syncthreads();                    // gates ready; all A reads done

        // ---- prefetch X_{t+1} into A (h-independent, off critical path) ----
        if (t + 1 < T_) {
            const v4i* xs = (const v4i*)(X + ((size_t)(t + 1) * B_ + m0) * E_);
#pragma unroll
            for (int i = 0; i < 2; ++i) {
                int idx = tid + i * 512;
                int r = idx >> 5, c8 = idx & 31;
                *(v4i*)&A_lds[r * LDA + c8 * 8] = xs[r * 32 + c8];
            }
        }

        // ---- cell math (f32), h -> bf16, agent-scope store (no fence) ----
        u32 hpack = 0;
#pragma unroll
        for (int q = 0; q < 2; ++q) {
            int n = cn2 + q;
            float ip = gates[         cm * 33 + n] + bias[n];
            float jp = gates[1056 +   cm * 33 + n] + bias[32 + n];
            float fp = gates[2112 +   cm * 33 + n] + bias[64 + n] + 1.0f;
            float op = gates[3168 +   cm * 33 + n] + bias[96 + n];
            float cc = fsig(fp) * cst[q] + fsig(ip) * ftanh_(jp);
            cst[q] = cc;
            hpack |= ((u32)f2bf(fsig(op) * ftanh_(cc))) << (16 * q);
        }
        __hip_atomic_store(&hs32[((size_t)t * B_ + m0 + cm) * 512 + (nc << 4) + (tid & 15)],
                           hpack, __ATOMIC_RELAXED, __HIP_MEMORY_SCOPE_AGENT);

        if (t + 1 < T_) {
            // ---- release: drain stores (already at coherence point), then flag ----
            asm volatile("s_waitcnt vmcnt(0)" ::: "memory");
            __syncthreads();
            if (tid == 0) {
                u32* p = &bar[mchunk * T_ + t];
                __hip_atomic_fetch_add(p, 1u, __ATOMIC_RELAXED, __HIP_MEMORY_SCOPE_AGENT);
                while (__hip_atomic_load(p, __ATOMIC_RELAXED, __HIP_MEMORY_SCOPE_AGENT) < 32u)
                    __builtin_amdgcn_s_sleep(2);
            }
            __syncthreads();
            // ---- stage h_t (agent-scope loads bypass L1/L2 -> always fresh) ----
#pragma unroll
            for (int i = 0; i < 16; ++i) {
                int idx = tid + i * 512;      // < 8192
                int r = idx >> 8, c = idx & 255;
                u64 v = __hip_atomic_load(&hu64[((size_t)t * B_ + m0 + r) * 256 + c],
                                          __ATOMIC_RELAXED, __HIP_MEMORY_SCOPE_AGENT);
                *(u64*)&A_lds[r * LDA + 256 + c * 4] = v;
            }
        }
    }
}

// ---------------- P3: preds = hs @ U + b2 ----------------
__global__ void proj_kernel(const u16* __restrict__ hs, const float* __restrict__ U,
                            const float* __restrict__ b2, float* __restrict__ out) {
    __shared__ float Ul[H_ * 5];
    int tid = threadIdx.x;
    for (int i = tid; i < H_ * 5; i += 256) Ul[i] = U[i];
    __syncthreads();
    int wv = tid >> 6, lane = tid & 63;
    int row = blockIdx.x * 4 + wv;          // t*256 + b
    int t = row >> 8, b = row & 255;
    const v4i* hp = (const v4i*)(hs + (size_t)row * H_);
    float p[5] = {0.f, 0.f, 0.f, 0.f, 0.f};
#pragma unroll
    for (int half = 0; half < 2; ++half) {
        v4i hv = hp[lane * 2 + half];
        u16 us[8];
        *(v4i*)us = hv;
#pragma unroll
        for (int j = 0; j < 8; ++j) {
            float hf = bf2f(us[j]);
            int k = lane * 16 + half * 8 + j;
#pragma unroll
            for (int c = 0; c < 5; ++c) p[c] += hf * Ul[k * 5 + c];
        }
    }
#pragma unroll
    for (int c = 0; c < 5; ++c)
        for (int off = 32; off > 0; off >>= 1)
            p[c] += __shfl_down(p[c], off, 64);
    if (lane == 0) {
#pragma unroll
        for (int c = 0; c < 5; ++c)
            out[((size_t)b * T_ + t) * 5 + c] = p[c] + b2[c];
    }
}

extern "C" void kernel_launch(void* const* d_in, const int* in_sizes, int n_in,
                              void* d_out, int out_size, void* d_ws, size_t ws_size,
                              hipStream_t stream) {
    const int*   tokens = (const int*)d_in[0];
    const float* emb    = (const float*)d_in[1];
    const float* W      = (const float*)d_in[2];
    const float* b_l    = (const float*)d_in[3];
    const float* U      = (const float*)d_in[4];
    const float* b2     = (const float*)d_in[5];
    float* out = (float*)d_out;

    char* ws = (char*)d_ws;
    u16* Wf  = (u16*)(ws + WS_WF);
    u16* X   = (u16*)(ws + WS_X);
    u16* hs  = (u16*)(ws + WS_HS);
    u32* bar = (u32*)(ws + WS_BAR);

    hipMemsetAsync(bar, 0, 8 * T_ * sizeof(u32), stream);
    prep_w<<<2560, 256, 0, stream>>>(W, Wf);
    prep_x<<<3840, 256, 0, stream>>>(tokens, emb, X);
    lstm_main<<<256, 512, 0, stream>>>(Wf, X, b_l, hs, bar);
    proj_kernel<<<7680, 256, 0, stream>>>(hs, U, b2, out);
}

// Round 3
// 668.565 us; speedup vs baseline: 6.3175x; 1.7652x over previous
//
#include <hip/hip_runtime.h>

typedef unsigned short u16;
typedef unsigned int u32;
typedef unsigned long long u64;
typedef int   v4i  __attribute__((ext_vector_type(4)));
typedef short v8s  __attribute__((ext_vector_type(8)));
typedef float v2f  __attribute__((ext_vector_type(2)));
typedef float v16f __attribute__((ext_vector_type(16)));

#define B_ 256
#define T_ 120
#define E_ 256
#define H_ 1024
#define K_ 1280
#define LDH 1032    // 1024 + 8 pad (u16 elems)
#define LDX 264     // 256 + 8 pad

// ---- ws layout (bytes) ----
#define WS_WF   0                    // 10,485,760  (W fragments, bf16)
#define WS_X    10485760             // 15,728,640  (X (T,B,E) bf16)
#define WS_HS   26214400             // 62,914,560  (hs (T,B,H) bf16)
#define WS_BAR  89128960             // 3,840

__device__ __forceinline__ u16 f2bf(float f) {
    union { float f; u32 u; } v; v.f = f;
    u32 r = v.u + 0x7fffu + ((v.u >> 16) & 1u);   // RNE
    return (u16)(r >> 16);
}
__device__ __forceinline__ float bf2f(u16 u) {
    union { u32 u; float f; } v; v.u = ((u32)u) << 16; return v.f;
}
__device__ __forceinline__ float fsig(float x) {
    float t = __builtin_amdgcn_exp2f(-1.44269504f * x);
    return __builtin_amdgcn_rcpf(1.0f + t);
}
__device__ __forceinline__ float ftanh_(float x) {
    float xc = fminf(8.0f, fmaxf(-8.0f, x));
    float t = __builtin_amdgcn_exp2f(2.88539008f * xc);
    return (t - 1.0f) * __builtin_amdgcn_rcpf(t + 1.0f);
}

// ---------------- P1: W (1280,4096) f32 -> bf16 32x32x16 B-fragments ----------------
// cid = nc*8 + g*2 + khalf (0..255); chunk = 40 frags f=0..39, global s = 2f+khalf
// (s-parity K-split so both K-half waves own 8 x-frags + 32 h-frags).
// frag elem: lane l, j0..7 -> B[k][col], k = s*16 + (l>>5)*8 + j, col = g*1024 + nc*32 + (l&31)
__global__ void prep_w(const float* __restrict__ W, u16* __restrict__ Wf) {
    int tg  = blockIdx.x * 256 + threadIdx.x;     // < 655360
    int l   = tg & 63;
    int fid = tg >> 6;                            // < 10240
    int f   = fid % 40;
    int cid = fid / 40;
    int khalf = cid & 1;
    int g   = (cid >> 1) & 3;
    int nc  = cid >> 3;
    int s   = 2 * f + khalf;                      // 0..79
    int kb  = s * 16 + ((l >> 5) << 3);
    int col = g * 1024 + nc * 32 + (l & 31);
    u16 o[8];
#pragma unroll
    for (int j = 0; j < 8; ++j)
        o[j] = f2bf(W[(size_t)(kb + j) * 4096 + col]);
    *(v4i*)(Wf + (((size_t)fid << 6) + l) * 8) = *(v4i*)o;
}

// ---------------- P2: embedding gather -> X (T,B,E) bf16 ----------------
__global__ void prep_x(const int* __restrict__ tokens, const float* __restrict__ emb,
                       u16* __restrict__ X) {
    int v   = blockIdx.x * 256 + threadIdx.x;     // < 983040
    int e8  = v & 31;
    int row = v >> 5;                             // t*256 + b
    int t = row >> 8, b = row & 255;
    int tok = tokens[b * T_ + t];
    const float* src = emb + (size_t)tok * E_ + e8 * 8;
    u16 o[8];
#pragma unroll
    for (int j = 0; j < 8; ++j) o[j] = f2bf(src[j]);
    *(v4i*)(X + (size_t)row * E_ + e8 * 8) = *(v4i*)o;
}

// ---------------- main persistent LSTM kernel ----------------
// 256 blocks x 512 threads. Block (mchunk=bid&7, nc=bid>>3): rows [m0,m0+32),
// hidden [nc*32,+32), all gates. Wave (g=wv>>1, khalf=wv&1): 32x32 tile of
// gate g over K-parity khalf. W pinned in 160 VGPRs (opaque asm, no remat).
// x-part MFMAs for step t+1 run under the inter-block barrier latency.
__global__ __launch_bounds__(512, 2) void lstm_main(
    const u16* __restrict__ Wf, const u16* __restrict__ X,
    const float* __restrict__ b_lstm, u16* __restrict__ hs,
    u32* __restrict__ bar) {

    __shared__ u16  hbuf[32 * LDH];          // 66,048 B
    __shared__ u16  xbuf[32 * LDX];          // 16,896 B
    __shared__ float gates[2 * 4 * 32 * 34]; // 34,816 B
    __shared__ float bias[128];

    const int tid   = threadIdx.x;
    const int lane  = tid & 63;
    const int wv    = tid >> 6;
    const int g     = wv >> 1;
    const int khalf = wv & 1;
    const int bid   = blockIdx.x;
    const int mchunk = bid & 7;
    const int nc    = bid >> 3;
    const int m0    = mchunk << 5;

    if (tid < 128) bias[tid] = b_lstm[(tid >> 5) * H_ + (nc << 5) + (tid & 31)];

    // ---- resident W fragments: 40 x v8s = 160 VGPR, pinned ----
    v8s Wr[40];
    {
        const int cid = nc * 8 + g * 2 + khalf;
        const v4i* wsrc = (const v4i*)(Wf + (size_t)cid * 40 * 512);
#pragma unroll
        for (int f = 0; f < 40; ++f)
            Wr[f] = __builtin_bit_cast(v8s, wsrc[f * 64 + lane]);
    }
#pragma unroll
    for (int f = 0; f < 40; ++f) asm volatile("" : "+v"(Wr[f]));

    // ---- stage X_0 ----
    {
        const v4i* xs = (const v4i*)(X + (size_t)m0 * E_);
#pragma unroll
        for (int i = 0; i < 2; ++i) {
            int idx = tid + i * 512;
            int r = idx >> 5, c8 = idx & 31;
            *(v4i*)&xbuf[r * LDX + c8 * 8] = xs[r * 32 + c8];
        }
    }
    __syncthreads();

    const u16* Ax = &xbuf[(lane & 31) * LDX + ((lane >> 5) << 3)];
    const u16* Ah = &hbuf[(lane & 31) * LDH + ((lane >> 5) << 3)];

    // ---- x-part MFMA for t=0 ----
    v16f acc = {0,0,0,0,0,0,0,0,0,0,0,0,0,0,0,0};
#pragma unroll
    for (int f = 0; f < 8; ++f) {
        v8s a = *(const v8s*)(Ax + (2 * f + khalf) * 16);
        acc = __builtin_amdgcn_mfma_f32_32x32x16_bf16(a, Wr[f], acc, 0, 0, 0);
    }

    float cst[2] = {0.f, 0.f};
    const int cm  = tid >> 4;
    const int cn2 = (tid & 15) << 1;
    u32* hs32 = (u32*)hs;

    for (int t = 0; t < T_; ++t) {
        if (t > 0) {
            // ---- wait for h_{t-1} (flag usually already set: hidden by x-MFMAs) ----
            if (tid == 0) {
                u32* p = &bar[mchunk * T_ + (t - 1)];
                while (__hip_atomic_load(p, __ATOMIC_RELAXED, __HIP_MEMORY_SCOPE_AGENT) < 32u)
                    __builtin_amdgcn_s_sleep(1);
            }
            __syncthreads();
            // ---- stage h_{t-1}: normal cached loads (addresses step-unique; L2 shared
            // within the m-group's XCD) ----
            {
                const v4i* hsrc = (const v4i*)(hs + ((size_t)(t - 1) * B_ + m0) * H_);
#pragma unroll
                for (int i = 0; i < 8; ++i) {
                    int idx = tid + i * 512;     // < 4096
                    int r = idx >> 7, c = idx & 127;
                    *(v4i*)&hbuf[r * LDH + c * 8] = hsrc[r * 128 + c];
                }
            }
            __syncthreads();
            // ---- h-part MFMA (f=8..39) ----
#pragma unroll
            for (int f = 8; f < 40; ++f) {
                v8s a = *(const v8s*)(Ah + ((2 * f + khalf) * 16 - 256));
                acc = __builtin_amdgcn_mfma_f32_32x32x16_bf16(a, Wr[f], acc, 0, 0, 0);
            }
        }

        // ---- partials -> LDS: C/D col=lane&31, row=(reg&3)+8*(reg>>2)+4*(lane>>5) ----
        {
            float* gb = &gates[((khalf << 2) + g) * 1088];
            int col = lane & 31, rq = (lane >> 5) << 2;
#pragma unroll
            for (int reg = 0; reg < 16; ++reg) {
                int row = (reg & 3) + ((reg >> 2) << 3) + rq;
                gb[row * 34 + col] = acc[reg];
            }
        }
        __syncthreads();

        // ---- cell math: sum K-halves, bias, activations ----
        u32 hpack = 0;
        {
            v2f zz[4];
#pragma unroll
            for (int gg = 0; gg < 4; ++gg) {
                v2f a = *(const v2f*)&gates[gg * 1088 + cm * 34 + cn2];
                v2f b = *(const v2f*)&gates[(4 + gg) * 1088 + cm * 34 + cn2];
                zz[gg].x = a.x + b.x; zz[gg].y = a.y + b.y;
            }
#pragma unroll
            for (int q = 0; q < 2; ++q) {
                int n = cn2 + q;
                float ip = zz[0][q] + bias[n];
                float jp = zz[1][q] + bias[32 + n];
                float fp = zz[2][q] + bias[64 + n] + 1.0f;
                float op = zz[3][q] + bias[96 + n];
                float cc = fsig(fp) * cst[q] + fsig(ip) * ftanh_(jp);
                cst[q] = cc;
                hpack |= ((u32)f2bf(fsig(op) * ftanh_(cc))) << (16 * q);
            }
        }
        __hip_atomic_store(&hs32[((size_t)t * B_ + m0 + cm) * 512 + (nc << 4) + (tid & 15)],
                           hpack, __ATOMIC_RELAXED, __HIP_MEMORY_SCOPE_AGENT);

        if (t + 1 < T_) {
            // ---- prefetch X_{t+1} (overwrites xbuf; prior reads done at t-top syncs) ----
            {
                const v4i* xs = (const v4i*)(X + ((size_t)(t + 1) * B_ + m0) * E_);
#pragma unroll
                for (int i = 0; i < 2; ++i) {
                    int idx = tid + i * 512;
                    int r = idx >> 5, c8 = idx & 31;
                    *(v4i*)&xbuf[r * LDX + c8 * 8] = xs[r * 32 + c8];
                }
            }
            asm volatile("s_waitcnt vmcnt(0)" ::: "memory");   // h stores drained
            __syncthreads();                                   // whole block drained
            if (tid == 0)
                __hip_atomic_fetch_add(&bar[mchunk * T_ + t], 1u,
                                       __ATOMIC_RELAXED, __HIP_MEMORY_SCOPE_AGENT);
            // ---- x-part MFMA for t+1 (hides barrier + other groups' progress) ----
#pragma unroll
            for (int reg = 0; reg < 16; ++reg) acc[reg] = 0.f;
#pragma unroll
            for (int f = 0; f < 8; ++f) {
                v8s a = *(const v8s*)(Ax + (2 * f + khalf) * 16);
                acc = __builtin_amdgcn_mfma_f32_32x32x16_bf16(a, Wr[f], acc, 0, 0, 0);
            }
        }
    }
}

// ---------------- P3: preds = hs @ U + b2 ----------------
__global__ void proj_kernel(const u16* __restrict__ hs, const float* __restrict__ U,
                            const float* __restrict__ b2, float* __restrict__ out) {
    __shared__ float Ul[H_ * 5];
    int tid = threadIdx.x;
    for (int i = tid; i < H_ * 5; i += 256) Ul[i] = U[i];
    __syncthreads();
    int wv = tid >> 6, lane = tid & 63;
    int row = blockIdx.x * 4 + wv;          // t*256 + b
    int t = row >> 8, b = row & 255;
    const v4i* hp = (const v4i*)(hs + (size_t)row * H_);
    float p[5] = {0.f, 0.f, 0.f, 0.f, 0.f};
#pragma unroll
    for (int half = 0; half < 2; ++half) {
        v4i hv = hp[lane * 2 + half];
        u16 us[8];
        *(v4i*)us = hv;
#pragma unroll
        for (int j = 0; j < 8; ++j) {
            float hf = bf2f(us[j]);
            int k = lane * 16 + half * 8 + j;
#pragma unroll
            for (int c = 0; c < 5; ++c) p[c] += hf * Ul[k * 5 + c];
        }
    }
#pragma unroll
    for (int c = 0; c < 5; ++c)
        for (int off = 32; off > 0; off >>= 1)
            p[c] += __shfl_down(p[c], off, 64);
    if (lane == 0) {
#pragma unroll
        for (int c = 0; c < 5; ++c)
            out[((size_t)b * T_ + t) * 5 + c] = p[c] + b2[c];
    }
}

extern "C" void kernel_launch(void* const* d_in, const int* in_sizes, int n_in,
                              void* d_out, int out_size, void* d_ws, size_t ws_size,
                              hipStream_t stream) {
    const int*   tokens = (const int*)d_in[0];
    const float* emb    = (const float*)d_in[1];
    const float* W      = (const float*)d_in[2];
    const float* b_l    = (const float*)d_in[3];
    const float* U      = (const float*)d_in[4];
    const float* b2     = (const float*)d_in[5];
    float* out = (float*)d_out;

    char* ws = (char*)d_ws;
    u16* Wf  = (u16*)(ws + WS_WF);
    u16* X   = (u16*)(ws + WS_X);
    u16* hs  = (u16*)(ws + WS_HS);
    u32* bar = (u32*)(ws + WS_BAR);

    hipMemsetAsync(bar, 0, 8 * T_ * sizeof(u32), stream);
    prep_w<<<2560, 256, 0, stream>>>(W, Wf);
    prep_x<<<3840, 256, 0, stream>>>(tokens, emb, X);
    lstm_main<<<256, 512, 0, stream>>>(Wf, X, b_l, hs, bar);
    proj_kernel<<<7680, 256, 0, stream>>>(hs, U, b2, out);
}

// Round 4
// 607.929 us; speedup vs baseline: 6.9476x; 1.0997x over previous
//
#include <hip/hip_runtime.h>

typedef unsigned short u16;
typedef unsigned int u32;
typedef unsigned long long u64;
typedef int   v4i  __attribute__((ext_vector_type(4)));
typedef short v8s  __attribute__((ext_vector_type(8)));
typedef float v2f  __attribute__((ext_vector_type(2)));
typedef float v16f __attribute__((ext_vector_type(16)));

#define B_ 256
#define T_ 120
#define E_ 256
#define H_ 1024
#define K_ 1280
#define LDH 1032    // 1024 + 8 pad (u16); row = 2064B, halves stay contiguous
#define LDX 264     // 256 + 8 pad

// ---- ws layout (bytes) ----
#define WS_WF   0                    // 10,485,760  (W fragments, bf16)
#define WS_X    10485760             // 15,728,640  (X (T,B,E) bf16)
#define WS_HS   26214400             // 62,914,560  (hs (T,B,H) bf16)
#define WS_BAR  89128960             // 3,840

__device__ __forceinline__ u16 f2bf(float f) {
    union { float f; u32 u; } v; v.f = f;
    u32 r = v.u + 0x7fffu + ((v.u >> 16) & 1u);   // RNE
    return (u16)(r >> 16);
}
__device__ __forceinline__ float bf2f(u16 u) {
    union { u32 u; float f; } v; v.u = ((u32)u) << 16; return v.f;
}
__device__ __forceinline__ float fsig(float x) {
    float t = __builtin_amdgcn_exp2f(-1.44269504f * x);
    return __builtin_amdgcn_rcpf(1.0f + t);
}
__device__ __forceinline__ float ftanh_(float x) {
    float xc = fminf(8.0f, fmaxf(-8.0f, x));
    float t = __builtin_amdgcn_exp2f(2.88539008f * xc);
    return (t - 1.0f) * __builtin_amdgcn_rcpf(t + 1.0f);
}
__device__ __forceinline__ void gl_lds16(const void* g, void* l) {
    __builtin_amdgcn_global_load_lds(
        (const __attribute__((address_space(1))) void*)g,
        (__attribute__((address_space(3))) void*)l, 16, 0, 0);
}

// ---------------- P1: W (1280,4096) f32 -> bf16 32x32x16 B-fragments ----------------
// cid = nc*8 + g*2 + khalf; frag f: s = 2f+khalf, elem (l,j):
//   W[s*16 + (l>>5)*8 + j][g*1024 + nc*32 + (l&31)].
// v2: coalesced reads + LDS transpose. Block = (cid, fo in 0..4) -> frags fo*8..fo*8+7.
__global__ void prep_w(const float* __restrict__ W, u16* __restrict__ Wf) {
    __shared__ u16 tile[32 * 136];        // [col 0..31][localk 0..127 + 8 pad]
    int bid = blockIdx.x;
    int cid = bid / 5, fo = bid % 5;
    int kh  = cid & 1, g = (cid >> 1) & 3, nc = cid >> 3;
    int colbase = g * 1024 + nc * 32;
    int tid = threadIdx.x;
    int c = tid & 31, r = tid >> 5;       // r 0..7

    // read: 8 frags x 16 k-rows x 32 cols, coalesced 128B per row
#pragma unroll
    for (int fl = 0; fl < 8; ++fl) {
        int k0 = (2 * (fo * 8 + fl) + kh) * 16;
#pragma unroll
        for (int rr = 0; rr < 2; ++rr) {
            int row = r + rr * 8;         // 0..15
            float v = W[(size_t)(k0 + row) * 4096 + colbase + c];
            tile[c * 136 + fl * 16 + row] = f2bf(v);
        }
    }
    __syncthreads();

    // emit: frag (l, j) <- tile[l&31][fl*16 + (l>>5)*8 + j], b128 reads, coalesced writes
    int lane = tid & 63;
#pragma unroll
    for (int pass = 0; pass < 2; ++pass) {
        int fl = (tid >> 6) + pass * 4;
        v4i o = *(const v4i*)&tile[(lane & 31) * 136 + fl * 16 + ((lane >> 5) << 3)];
        *(v4i*)(Wf + (((size_t)(cid * 40 + fo * 8 + fl)) << 9) + lane * 8) = o;
    }
}

// ---------------- P2: embedding gather -> X (T,B,E) bf16 ----------------
__global__ void prep_x(const int* __restrict__ tokens, const float* __restrict__ emb,
                       u16* __restrict__ X) {
    int v   = blockIdx.x * 256 + threadIdx.x;     // < 983040
    int e8  = v & 31;
    int row = v >> 5;                             // t*256 + b
    int t = row >> 8, b = row & 255;
    int tok = tokens[b * T_ + t];
    const float* src = emb + (size_t)tok * E_ + e8 * 8;
    u16 o[8];
#pragma unroll
    for (int j = 0; j < 8; ++j) o[j] = f2bf(src[j]);
    *(v4i*)(X + (size_t)row * E_ + e8 * 8) = *(v4i*)o;
}

// ---------------- main persistent LSTM kernel ----------------
// 256 blocks x 512 threads. Block (mchunk=bid&7, nc=bid>>3). Wave (g=wv>>1,
// khalf=wv&1): 32x32 gate tile, K-parity split. W pinned in registers.
// h staged async via global_load_lds in 2 pipelined 512-col chunks with raw
// s_waitcnt vmcnt(N)+s_barrier; x-part MFMAs for t+1 hide the flag handshake.
__global__ __launch_bounds__(512, 2) void lstm_main(
    const u16* __restrict__ Wf, const u16* __restrict__ X,
    const float* __restrict__ b_lstm, u16* __restrict__ hs,
    u32* __restrict__ bar) {

    __shared__ u16  hbuf[32 * LDH];          // 66,048 B
    __shared__ u16  xbuf[32 * LDX];          // 16,896 B
    __shared__ float gates[2 * 4 * 32 * 34]; // 34,816 B
    __shared__ float bias[128];

    const int tid   = threadIdx.x;
    const int lane  = tid & 63;
    const int wv    = tid >> 6;
    const int g     = wv >> 1;
    const int khalf = wv & 1;
    const int bid   = blockIdx.x;
    const int mchunk = bid & 7;
    const int nc    = bid >> 3;
    const int m0    = mchunk << 5;

    if (tid < 128) bias[tid] = b_lstm[(tid >> 5) * H_ + (nc << 5) + (tid & 31)];

    // ---- resident W fragments: 40 x v8s, pinned ----
    v8s Wr[40];
    {
        const int cid = nc * 8 + g * 2 + khalf;
        const v4i* wsrc = (const v4i*)(Wf + (size_t)cid * 40 * 512);
#pragma unroll
        for (int f = 0; f < 40; ++f)
            Wr[f] = __builtin_bit_cast(v8s, wsrc[f * 64 + lane]);
    }
#pragma unroll
    for (int f = 0; f < 40; ++f) asm volatile("" : "+v"(Wr[f]));

    // ---- stage X_0 ----
    {
        const v4i* xs = (const v4i*)(X + (size_t)m0 * E_);
#pragma unroll
        for (int i = 0; i < 2; ++i) {
            int idx = tid + i * 512;
            int r = idx >> 5, c8 = idx & 31;
            *(v4i*)&xbuf[r * LDX + c8 * 8] = xs[r * 32 + c8];
        }
    }
    __syncthreads();

    const u16* Ax = &xbuf[(lane & 31) * LDX + ((lane >> 5) << 3)];
    const u16* Ah = &hbuf[(lane & 31) * LDH + ((lane >> 5) << 3)];

    // ---- x-part MFMA for t=0 ----
    v16f acc = {0,0,0,0,0,0,0,0,0,0,0,0,0,0,0,0};
#pragma unroll
    for (int f = 0; f < 8; ++f) {
        v8s a = *(const v8s*)(Ax + (2 * f + khalf) * 16);
        acc = __builtin_amdgcn_mfma_f32_32x32x16_bf16(a, Wr[f], acc, 0, 0, 0);
    }

    float cst[2] = {0.f, 0.f};
    const int cm  = tid >> 4;
    const int cn2 = (tid & 15) << 1;
    u32* hs32 = (u32*)hs;

    for (int t = 0; t < T_; ++t) {
        if (t > 0) {
            // ---- wait for h_{t-1} flag (usually already set: hidden by x-MFMAs) ----
            if (tid == 0) {
                u32* p = &bar[mchunk * T_ + (t - 1)];
                while (__hip_atomic_load(p, __ATOMIC_RELAXED, __HIP_MEMORY_SCOPE_AGENT) < 32u)
                    __builtin_amdgcn_s_sleep(1);
            }
            __syncthreads();
            // ---- issue async h loads: wave wv -> rows [wv*4, wv*4+4), halves 0,1 ----
            {
                const u16* srcb = hs + ((size_t)(t - 1) * B_ + m0) * H_;
                int r0 = wv << 2;
#pragma unroll
                for (int half = 0; half < 2; ++half)
#pragma unroll
                    for (int i = 0; i < 4; ++i) {
                        int r = r0 + i;
                        gl_lds16(srcb + (size_t)r * H_ + half * 512 + lane * 8,
                                 &hbuf[r * LDH + half * 512]);
                    }
            }
            // ---- chunk A: cols [0,512) ready after own-wave vmcnt(4) + barrier ----
            asm volatile("s_waitcnt vmcnt(4)\n\ts_barrier" ::: "memory");
#pragma unroll
            for (int f = 8; f < 24; ++f) {
                v8s a = *(const v8s*)(Ah + ((2 * f + khalf) * 16 - 256));
                acc = __builtin_amdgcn_mfma_f32_32x32x16_bf16(a, Wr[f], acc, 0, 0, 0);
            }
            // ---- chunk B: cols [512,1024) ----
            asm volatile("s_waitcnt vmcnt(0)\n\ts_barrier" ::: "memory");
#pragma unroll
            for (int f = 24; f < 40; ++f) {
                v8s a = *(const v8s*)(Ah + ((2 * f + khalf) * 16 - 256));
                acc = __builtin_amdgcn_mfma_f32_32x32x16_bf16(a, Wr[f], acc, 0, 0, 0);
            }
        }

        // ---- partials -> LDS: C/D col=lane&31, row=(reg&3)+8*(reg>>2)+4*(lane>>5) ----
        {
            float* gb = &gates[((khalf << 2) + g) * 1088];
            int col = lane & 31, rq = (lane >> 5) << 2;
#pragma unroll
            for (int reg = 0; reg < 16; ++reg) {
                int row = (reg & 3) + ((reg >> 2) << 3) + rq;
                gb[row * 34 + col] = acc[reg];
            }
        }
        __syncthreads();

        // ---- prefetch X_{t+1} (issues early; overlaps cell transcendentals) ----
        if (t + 1 < T_) {
            const v4i* xs = (const v4i*)(X + ((size_t)(t + 1) * B_ + m0) * E_);
#pragma unroll
            for (int i = 0; i < 2; ++i) {
                int idx = tid + i * 512;
                int r = idx >> 5, c8 = idx & 31;
                *(v4i*)&xbuf[r * LDX + c8 * 8] = xs[r * 32 + c8];
            }
        }

        // ---- cell math: sum K-halves, bias, activations ----
        u32 hpack = 0;
        {
            v2f zz[4];
#pragma unroll
            for (int gg = 0; gg < 4; ++gg) {
                v2f a = *(const v2f*)&gates[gg * 1088 + cm * 34 + cn2];
                v2f b = *(const v2f*)&gates[(4 + gg) * 1088 + cm * 34 + cn2];
                zz[gg].x = a.x + b.x; zz[gg].y = a.y + b.y;
            }
#pragma unroll
            for (int q = 0; q < 2; ++q) {
                int n = cn2 + q;
                float ip = zz[0][q] + bias[n];
                float jp = zz[1][q] + bias[32 + n];
                float fp = zz[2][q] + bias[64 + n] + 1.0f;
                float op = zz[3][q] + bias[96 + n];
                float cc = fsig(fp) * cst[q] + fsig(ip) * ftanh_(jp);
                cst[q] = cc;
                hpack |= ((u32)f2bf(fsig(op) * ftanh_(cc))) << (16 * q);
            }
        }
        __hip_atomic_store(&hs32[((size_t)t * B_ + m0 + cm) * 512 + (nc << 4) + (tid & 15)],
                           hpack, __ATOMIC_RELAXED, __HIP_MEMORY_SCOPE_AGENT);

        if (t + 1 < T_) {
            // ---- release: each wave drains its own VM ops, barrier, then flag ----
            asm volatile("s_waitcnt vmcnt(0)" ::: "memory");
            __syncthreads();
            if (tid == 0)
                __hip_atomic_fetch_add(&bar[mchunk * T_ + t], 1u,
                                       __ATOMIC_RELAXED, __HIP_MEMORY_SCOPE_AGENT);
            // ---- x-part MFMA for t+1 (hides handshake latency) ----
#pragma unroll
            for (int reg = 0; reg < 16; ++reg) acc[reg] = 0.f;
#pragma unroll
            for (int f = 0; f < 8; ++f) {
                v8s a = *(const v8s*)(Ax + (2 * f + khalf) * 16);
                acc = __builtin_amdgcn_mfma_f32_32x32x16_bf16(a, Wr[f], acc, 0, 0, 0);
            }
        }
    }
}

// ---------------- P3: preds = hs @ U + b2 (64 rows/block; U staged once) ----------------
__global__ void proj_kernel(const u16* __restrict__ hs, const float* __restrict__ U,
                            const float* __restrict__ b2, float* __restrict__ out) {
    __shared__ float Ul[H_ * 5];
    int tid = threadIdx.x;
    for (int i = tid; i < H_ * 5; i += 256) Ul[i] = U[i];
    __syncthreads();
    int wv = tid >> 6, lane = tid & 63;
#pragma unroll 1
    for (int i = 0; i < 16; ++i) {
        int row = blockIdx.x * 64 + wv * 16 + i;   // t*256 + b, < 30720
        int t = row >> 8, b = row & 255;
        const v4i* hp = (const v4i*)(hs + (size_t)row * H_);
        float p[5] = {0.f, 0.f, 0.f, 0.f, 0.f};
#pragma unroll
        for (int half = 0; half < 2; ++half) {
            v4i hv = hp[lane * 2 + half];
            u16 us[8];
            *(v4i*)us = hv;
#pragma unroll
            for (int j = 0; j < 8; ++j) {
                float hf = bf2f(us[j]);
                int k = lane * 16 + half * 8 + j;
#pragma unroll
                for (int c = 0; c < 5; ++c) p[c] += hf * Ul[k * 5 + c];
            }
        }
#pragma unroll
        for (int c = 0; c < 5; ++c)
            for (int off = 32; off > 0; off >>= 1)
                p[c] += __shfl_down(p[c], off, 64);
        if (lane == 0) {
#pragma unroll
            for (int c = 0; c < 5; ++c)
                out[((size_t)b * T_ + t) * 5 + c] = p[c] + b2[c];
        }
    }
}

extern "C" void kernel_launch(void* const* d_in, const int* in_sizes, int n_in,
                              void* d_out, int out_size, void* d_ws, size_t ws_size,
                              hipStream_t stream) {
    const int*   tokens = (const int*)d_in[0];
    const float* emb    = (const float*)d_in[1];
    const float* W      = (const float*)d_in[2];
    const float* b_l    = (const float*)d_in[3];
    const float* U      = (const float*)d_in[4];
    const float* b2     = (const float*)d_in[5];
    float* out = (float*)d_out;

    char* ws = (char*)d_ws;
    u16* Wf  = (u16*)(ws + WS_WF);
    u16* X   = (u16*)(ws + WS_X);
    u16* hs  = (u16*)(ws + WS_HS);
    u32* bar = (u32*)(ws + WS_BAR);

    hipMemsetAsync(bar, 0, 8 * T_ * sizeof(u32), stream);
    prep_w<<<1280, 256, 0, stream>>>(W, Wf);
    prep_x<<<3840, 256, 0, stream>>>(tokens, emb, X);
    lstm_main<<<256, 512, 0, stream>>>(Wf, X, b_l, hs, bar);
    proj_kernel<<<480, 256, 0, stream>>>(hs, U, b2, out);
}